// Round 14
// baseline (409.147 us; speedup 1.0000x reference)
//
#include <hip/hip_runtime.h>
#include <hip/hip_bf16.h>

// Shapes are fixed by the problem definition.
#define B_   16
#define T_   4096
#define N_   512
#define D_   512
#define EPSF 1e-8f

typedef __attribute__((ext_vector_type(4))) float f32x4;

// round-to-nearest-even f32 -> bf16, packed pair into one u32 (unused in
// GEMM path now; kept for reference)
__device__ __forceinline__ unsigned int pack2bf(float a, float b) {
  unsigned int ua = __float_as_uint(a);
  ua += 0x7fffu + ((ua >> 16) & 1u);
  unsigned int ub = __float_as_uint(b);
  ub += 0x7fffu + ((ub >> 16) & 1u);
  return (ua >> 16) | (ub & 0xffff0000u);
}

// 4 f32 -> 4 fp8 e4m3 (OCP) packed into one u32, byte i = elem i
__device__ __forceinline__ unsigned int pack4fp8(float4 v) {
  int u = __builtin_amdgcn_cvt_pk_fp8_f32(v.x, v.y, 0, false);   // bytes 0,1
  u = __builtin_amdgcn_cvt_pk_fp8_f32(v.z, v.w, u, true);        // bytes 2,3
  return (unsigned int)u;
}

// async global->LDS, 16 B per lane
__device__ __forceinline__ void gload_lds16(const void* g, void* l) {
  __builtin_amdgcn_global_load_lds(
      (const __attribute__((address_space(1))) unsigned int*)g,
      (__attribute__((address_space(3))) unsigned int*)l, 16, 0, 0);
}

// ---------------------------------------------------------------------------
// Kernel A: distractor rows -> inv_nd (f32 norms) + fp8 e4m3 copy (ydq).
// ---------------------------------------------------------------------------
__global__ void rownorms_d(const float* __restrict__ yd,
                           float* __restrict__ inv_nd,
                           unsigned char* __restrict__ ydq) {
  const int tid = threadIdx.x;
  const int g   = tid >> 4;
  const int t   = tid & 15;
  const int row = blockIdx.x * 16 + g;
  const float* dr = yd + (size_t)row * D_;
  unsigned char* ob = ydq + (size_t)row * D_;

  float dd = 0.f;
#pragma unroll
  for (int k = 0; k < 8; ++k) {
    const int col = k * 64 + t * 4;
    float4 a = *(const float4*)(dr + col);
    dd += a.x * a.x + a.y * a.y + a.z * a.z + a.w * a.w;
    *(unsigned int*)(ob + col) = pack4fp8(a);   // byte index == elem index
  }
#pragma unroll
  for (int m = 1; m < 16; m <<= 1) dd += __shfl_xor(dd, m);
  if (t == 0) inv_nd[row] = 1.f / fmaxf(sqrtf(dd), EPSF);
}

// B staging (fp8): 512 rows x 64 k-elems = 32 KB per K-tile.
// 16B-granularity swizzle (gload-compatible): LDS[row][c16] = G[row][c16 ^
// (row&3)] (involution). Read applies the same XOR at 16B level; the 8B
// half-select (c8&1) is unswizzled. ds_read_b64 lands ~4-way (1.58x, off
// the critical path).
__device__ __forceinline__ void stage_B(unsigned char* buf,
                                        const unsigned char* __restrict__ Bq,
                                        int k0, int tid) {
#pragma unroll
  for (int j = 0; j < 4; ++j) {
    const int g   = j * 512 + tid;          // 16B chunk 0..2047
    const int row = g >> 2;                 // 4 chunks per 64B row
    const int c16 = (g & 3) ^ (row & 3);    // inverse-swizzled source chunk
    gload_lds16(Bq + (size_t)row * D_ + k0 + (c16 << 4), buf + (g << 4));
  }
}

// A+T: issue 4 float4 of c and 4 float4 of yt into regs (early issue).
__device__ __forceinline__ void load_AT(const float* __restrict__ Ab,
                                        const float* __restrict__ Tb,
                                        int k0, int tid,
                                        float4* va, float4* vb) {
#pragma unroll
  for (int j = 0; j < 4; ++j) {
    const int g   = j * 512 + tid;          // float4 0..2047
    const int row = g >> 4;                 // 16 float4 per 64-col row
    const int c4  = g & 15;
    const size_t off = (size_t)row * D_ + k0 + (c4 << 2);
    va[j] = *(const float4*)(Ab + off);
    vb[j] = *(const float4*)(Tb + off);
  }
}

// cvt(fp8) + swizzled LDS write of A + stats accumulate.
// A LDS: 128 rows x 64B. 8B-chunk swizzle c8' = c8 ^ (row&7); the 4B
// half (c4&1) unswizzled. Write 2-way free; read (b64) 2-way free (audited).
__device__ __forceinline__ void writeA_stats(unsigned char* As,
                                             const float4* va, const float4* vb,
                                             int tid,
                                             float* cc, float* tt, float* ct) {
#pragma unroll
  for (int j = 0; j < 4; ++j) {
    const int g   = j * 512 + tid;
    const int row = g >> 4;
    const int c4  = g & 15;
    const int off = (row << 6) + ((((c4 >> 1) ^ (row & 7))) << 3) + ((c4 & 1) << 2);
    *(unsigned int*)(As + off) = pack4fp8(va[j]);
    cc[j] += va[j].x * va[j].x + va[j].y * va[j].y + va[j].z * va[j].z + va[j].w * va[j].w;
    tt[j] += vb[j].x * vb[j].x + vb[j].y * vb[j].y + vb[j].z * vb[j].z + vb[j].w * vb[j].w;
    ct[j] += va[j].x * vb[j].x + va[j].y * vb[j].y + va[j].z * vb[j].z + va[j].w * vb[j].w;
  }
}

// ---------------------------------------------------------------------------
// Kernel B (r14 = r11 + fp8 score-GEMM).
// Model: time ~= per-CU VMEM bytes at ~10 B/cyc/CU (r13 evidence: FETCH
// -29MB via XCD-affinity changed nothing; L3-warm replays identical).
// fp8 B halves the dominant per-iter term: 128 KB -> 96 KB (-25%).
// Positive-pair path (stats -> rt) stays f32. Structure r11-verbatim.
// LDS: 2x32K Bs + 8K As + 2.5K stats = 74.5 KB; frags halve -> fits 128
// VGPR -> __launch_bounds__(512,4) = 2 blocks/CU.
// ---------------------------------------------------------------------------
__launch_bounds__(512, 4)
__global__ void fused_ct(const float* __restrict__ c,
                         const float* __restrict__ yt,
                         const unsigned char* __restrict__ ydq,
                         const float* __restrict__ inv_nd,
                         float* __restrict__ rt,
                         float* __restrict__ S) {
  __shared__ __align__(16) unsigned char As[128 * 64];        // 8 KB
  __shared__ __align__(16) unsigned char Bs[2][512 * 64];     // 2x32 KB
  __shared__ float s_invc[128];
  __shared__ float s_invd[512];

  const int mt = blockIdx.x;
  const int b  = blockIdx.y;
  const int tid  = threadIdx.x;
  const int lane = tid & 63;
  const int w    = tid >> 6;
  const int wm   = w >> 2, wn = w & 3;   // 2 x 4 waves over 128 x 512 out

  const float* Ab = c  + ((size_t)b * T_ + (size_t)mt * 128) * D_;
  const float* Tb = yt + ((size_t)b * T_ + (size_t)mt * 128) * D_;
  const unsigned char* Bq = ydq + (size_t)b * N_ * D_;

  float4 va[4], vb[4];
  float cc[4] = {0.f, 0.f, 0.f, 0.f};
  float tt[4] = {0.f, 0.f, 0.f, 0.f};
  float ct[4] = {0.f, 0.f, 0.f, 0.f};

  // ---- prologue: iter-0 staging ----
  stage_B(Bs[0], Bq, 0, tid);            // async into Bs[0]
  load_AT(Ab, Tb, 0, tid, va, vb);
  s_invd[tid] = inv_nd[b * N_ + tid];
  writeA_stats(As, va, vb, tid, cc, tt, ct);
  __syncthreads();                       // As visible; Bs[0] gloads drained

  f32x4 acc[4][8] = {};

  // ---- K-loop: 8 iters of BK=64, double-buffered B, stage-before-compute --
  for (int k0i = 0; k0i < 8; ++k0i) {
    const bool more = (k0i < 7);
    if (more) {
      stage_B(Bs[(k0i + 1) & 1], Bq, (k0i + 1) * 64, tid);  // async, other buf
      load_AT(Ab, Tb, (k0i + 1) * 64, tid, va, vb);         // regs, early
    }

#pragma unroll
    for (int ks = 0; ks < 2; ++ks) {
      long af[4], bfr[8];
#pragma unroll
      for (int i = 0; i < 4; ++i) {
        const int ar = wm * 64 + i * 16 + (lane & 15);
        const int c8 = ks * 4 + (lane >> 4);
        af[i] = *(const long*)(As + (ar << 6) + ((c8 ^ (ar & 7)) << 3));
      }
#pragma unroll
      for (int n = 0; n < 8; ++n) {
        const int br = wn * 128 + n * 16 + (lane & 15);
        const int c8 = ks * 4 + (lane >> 4);
        bfr[n] = *(const long*)(Bs[k0i & 1] + (br << 6) +
                                (((c8 >> 1) ^ (br & 3)) << 4) + ((c8 & 1) << 3));
      }
#pragma unroll
      for (int mi = 0; mi < 4; ++mi)
#pragma unroll
        for (int ni = 0; ni < 8; ++ni)
          acc[mi][ni] = __builtin_amdgcn_mfma_f32_16x16x32_fp8_fp8(
              af[mi], bfr[ni], acc[mi][ni], 0, 0, 0);
    }

    __syncthreads();   // drains stageB(t+1)+loadA(t+1) — hidden under compute
    if (more) {
      writeA_stats(As, va, vb, tid, cc, tt, ct);  // short VALU+LDS window
      __syncthreads();                            // As(t+1) visible
    }
  }

  // ---- stats reduction (16-lane groups; rows j*32+(tid>>4)) ----
#pragma unroll
  for (int j = 0; j < 4; ++j) {
#pragma unroll
    for (int m = 1; m < 16; m <<= 1) {
      cc[j] += __shfl_xor(cc[j], m);
      tt[j] += __shfl_xor(tt[j], m);
      ct[j] += __shfl_xor(ct[j], m);
    }
    if ((tid & 15) == 0) {
      const int row = j * 32 + (tid >> 4);
      const float nc = fmaxf(sqrtf(cc[j]), EPSF);
      const float nt = fmaxf(sqrtf(tt[j]), EPSF);
      s_invc[row] = 1.f / nc;
      rt[b * T_ + mt * 128 + row] = ct[j] / (nt * nc);
    }
  }
  __syncthreads();

  // ---- epilogue: exp(acc*invc*invd) row-sum over all 512 cols ----
  float invd[8];
#pragma unroll
  for (int ni = 0; ni < 8; ++ni)
    invd[ni] = s_invd[wn * 128 + ni * 16 + (lane & 15)];

#pragma unroll
  for (int mi = 0; mi < 4; ++mi) {
    const int t0l = wm * 64 + mi * 16 + ((lane >> 4) << 2);  // local row
#pragma unroll
    for (int r = 0; r < 4; ++r) {
      const float invc = s_invc[t0l + r];
      float s = 0.f;
#pragma unroll
      for (int ni = 0; ni < 8; ++ni)
        s += __expf(acc[mi][ni][r] * invc * invd[ni]);
      s += __shfl_xor(s, 1);
      s += __shfl_xor(s, 2);
      s += __shfl_xor(s, 4);
      s += __shfl_xor(s, 8);
      if ((lane & 15) == 0)
        atomicAdd(&S[b * T_ + mt * 128 + t0l + r], s);
    }
  }
}

// ---------------------------------------------------------------------------
// Kernel C: loss = sum_{b,t} log(S + exp(r_t)) - r_t
// ---------------------------------------------------------------------------
__global__ void final_loss(const float* __restrict__ S,
                           const float* __restrict__ rt,
                           float* __restrict__ out) {
  const int tid = threadIdx.x;
  float sum = 0.f;
  for (int i = blockIdx.x * blockDim.x + tid; i < B_ * T_;
       i += gridDim.x * blockDim.x) {
    const float r = rt[i];
    sum += logf(S[i] + __expf(r)) - r;
  }
#pragma unroll
  for (int m = 32; m; m >>= 1) sum += __shfl_xor(sum, m);
  __shared__ float ws[4];
  if ((tid & 63) == 0) ws[tid >> 6] = sum;
  __syncthreads();
  if (tid == 0) atomicAdd(out, ws[0] + ws[1] + ws[2] + ws[3]);
}

// ---------------------------------------------------------------------------
extern "C" void kernel_launch(void* const* d_in, const int* in_sizes, int n_in,
                              void* d_out, int out_size, void* d_ws, size_t ws_size,
                              hipStream_t stream) {
  (void)in_sizes; (void)n_in; (void)out_size; (void)ws_size;
  const float* c  = (const float*)d_in[0];
  const float* yt = (const float*)d_in[1];
  const float* yd = (const float*)d_in[2];
  float* out = (float*)d_out;

  // ws layout: [ydq: B*N*D u8][rt: B*T f][inv_nd: B*N f][S: B*T f]
  const size_t ydq_n = (size_t)B_ * N_ * D_;    // 4.2M bytes = 4 MiB
  unsigned char* ydq = (unsigned char*)d_ws;
  float* rt     = (float*)(ydq + ydq_n);        // B*T
  float* inv_nd = rt + B_ * T_;                 // B*N
  float* S      = inv_nd + B_ * N_;             // B*T

  hipMemsetAsync(S, 0, (size_t)B_ * T_ * sizeof(float), stream);
  hipMemsetAsync(out, 0, sizeof(float), stream);

  rownorms_d<<<B_ * N_ / 16, 256, 0, stream>>>(yd, inv_nd, ydq);

  dim3 gF(T_ / 128, B_);   // (32, 16) = 512 blocks, 512 threads
  fused_ct<<<gF, 512, 0, stream>>>(c, yt, ydq, inv_nd, rt, S);

  final_loss<<<64, 256, 0, stream>>>(S, rt, out);
}

// Round 15
// 95.196 us; speedup vs baseline: 4.2979x; 4.2979x over previous
//
#include <hip/hip_runtime.h>
#include <hip/hip_bf16.h>

// Shapes are fixed by the problem definition.
#define B_   16
#define T_   4096
#define N_   512
#define D_   512
#define EPSF 1e-8f

typedef __attribute__((ext_vector_type(4))) float f32x4;

// 4 f32 -> 4 fp8 e4m3 (OCP) packed into one u32, byte i = elem i
__device__ __forceinline__ unsigned int pack4fp8(float4 v) {
  int u = __builtin_amdgcn_cvt_pk_fp8_f32(v.x, v.y, 0, false);   // bytes 0,1
  u = __builtin_amdgcn_cvt_pk_fp8_f32(v.z, v.w, u, true);        // bytes 2,3
  return (unsigned int)u;
}

// async global->LDS, 16 B per lane
__device__ __forceinline__ void gload_lds16(const void* g, void* l) {
  __builtin_amdgcn_global_load_lds(
      (const __attribute__((address_space(1))) unsigned int*)g,
      (__attribute__((address_space(3))) unsigned int*)l, 16, 0, 0);
}

// ---------------------------------------------------------------------------
// Kernel A: distractor rows -> inv_nd (f32 norms) + fp8 e4m3 copy (ydq).
// ---------------------------------------------------------------------------
__global__ void rownorms_d(const float* __restrict__ yd,
                           float* __restrict__ inv_nd,
                           unsigned char* __restrict__ ydq) {
  const int tid = threadIdx.x;
  const int g   = tid >> 4;
  const int t   = tid & 15;
  const int row = blockIdx.x * 16 + g;
  const float* dr = yd + (size_t)row * D_;
  unsigned char* ob = ydq + (size_t)row * D_;

  float dd = 0.f;
#pragma unroll
  for (int k = 0; k < 8; ++k) {
    const int col = k * 64 + t * 4;
    float4 a = *(const float4*)(dr + col);
    dd += a.x * a.x + a.y * a.y + a.z * a.z + a.w * a.w;
    *(unsigned int*)(ob + col) = pack4fp8(a);   // byte index == elem index
  }
#pragma unroll
  for (int m = 1; m < 16; m <<= 1) dd += __shfl_xor(dd, m);
  if (t == 0) inv_nd[row] = 1.f / fmaxf(sqrtf(dd), EPSF);
}

// B staging (fp8): 512 rows x 64 k-elems = 32 KB per K-tile.
// 16B-granularity swizzle (gload-compatible): LDS[row][c16] = G[row][c16 ^
// (row&3)] (involution). Read applies the same XOR at 16B level; ~4-way
// on the b64 read (1.58x, off the critical path; 7.3M counter confirmed r14).
__device__ __forceinline__ void stage_B(unsigned char* buf,
                                        const unsigned char* __restrict__ Bq,
                                        int k0, int tid) {
#pragma unroll
  for (int j = 0; j < 4; ++j) {
    const int g   = j * 512 + tid;          // 16B chunk 0..2047
    const int row = g >> 2;                 // 4 chunks per 64B row
    const int c16 = (g & 3) ^ (row & 3);    // inverse-swizzled source chunk
    gload_lds16(Bq + (size_t)row * D_ + k0 + (c16 << 4), buf + (g << 4));
  }
}

// A+T: issue 4 float4 of c and 4 float4 of yt into regs (early issue).
__device__ __forceinline__ void load_AT(const float* __restrict__ Ab,
                                        const float* __restrict__ Tb,
                                        int k0, int tid,
                                        float4* va, float4* vb) {
#pragma unroll
  for (int j = 0; j < 4; ++j) {
    const int g   = j * 512 + tid;          // float4 0..2047
    const int row = g >> 4;                 // 16 float4 per 64-col row
    const int c4  = g & 15;
    const size_t off = (size_t)row * D_ + k0 + (c4 << 2);
    va[j] = *(const float4*)(Ab + off);
    vb[j] = *(const float4*)(Tb + off);
  }
}

// cvt(fp8) + swizzled LDS write of A + stats accumulate.
// A LDS: 128 rows x 64B. 8B-chunk swizzle c8' = c8 ^ (row&7); the 4B
// half (c4&1) unswizzled. Write 2-way free; read (b64) 2-way free.
__device__ __forceinline__ void writeA_stats(unsigned char* As,
                                             const float4* va, const float4* vb,
                                             int tid,
                                             float* cc, float* tt, float* ct) {
#pragma unroll
  for (int j = 0; j < 4; ++j) {
    const int g   = j * 512 + tid;
    const int row = g >> 4;
    const int c4  = g & 15;
    const int off = (row << 6) + ((((c4 >> 1) ^ (row & 7))) << 3) + ((c4 & 1) << 2);
    *(unsigned int*)(As + off) = pack4fp8(va[j]);
    cc[j] += va[j].x * va[j].x + va[j].y * va[j].y + va[j].z * va[j].z + va[j].w * va[j].w;
    tt[j] += vb[j].x * vb[j].x + vb[j].y * vb[j].y + vb[j].z * vb[j].z + vb[j].w * vb[j].w;
    ct[j] += va[j].x * vb[j].x + va[j].y * vb[j].y + va[j].z * vb[j].z + va[j].w * vb[j].w;
  }
}

// ---------------------------------------------------------------------------
// Kernel B (r15 = r14 with the spill fixed: __launch_bounds__(512,2)).
// r14's (512,4) capped VGPR at 64 -> acc[4][8]+frags spilled to scratch
// (WRITE_SIZE 843 MB, 409 us). (512,2) allows ~220 VGPR, no spill — the
// r11 configuration. fp8 B-operand cuts per-iter VMEM demand 128->96 KB
// (-25%) under the demand-rate model (time ~ per-CU VMEM bytes at
// ~10 B/cyc/CU, validated r4-r13). Positive-pair path stays f32.
// ---------------------------------------------------------------------------
__launch_bounds__(512, 2)
__global__ void fused_ct(const float* __restrict__ c,
                         const float* __restrict__ yt,
                         const unsigned char* __restrict__ ydq,
                         const float* __restrict__ inv_nd,
                         float* __restrict__ rt,
                         float* __restrict__ S) {
  __shared__ __align__(16) unsigned char As[128 * 64];        // 8 KB
  __shared__ __align__(16) unsigned char Bs[2][512 * 64];     // 2x32 KB
  __shared__ float s_invc[128];
  __shared__ float s_invd[512];

  const int mt = blockIdx.x;
  const int b  = blockIdx.y;
  const int tid  = threadIdx.x;
  const int lane = tid & 63;
  const int w    = tid >> 6;
  const int wm   = w >> 2, wn = w & 3;   // 2 x 4 waves over 128 x 512 out

  const float* Ab = c  + ((size_t)b * T_ + (size_t)mt * 128) * D_;
  const float* Tb = yt + ((size_t)b * T_ + (size_t)mt * 128) * D_;
  const unsigned char* Bq = ydq + (size_t)b * N_ * D_;

  float4 va[4], vb[4];
  float cc[4] = {0.f, 0.f, 0.f, 0.f};
  float tt[4] = {0.f, 0.f, 0.f, 0.f};
  float ct[4] = {0.f, 0.f, 0.f, 0.f};

  // ---- prologue: iter-0 staging ----
  stage_B(Bs[0], Bq, 0, tid);            // async into Bs[0]
  load_AT(Ab, Tb, 0, tid, va, vb);
  s_invd[tid] = inv_nd[b * N_ + tid];
  writeA_stats(As, va, vb, tid, cc, tt, ct);
  __syncthreads();                       // As visible; Bs[0] gloads drained

  f32x4 acc[4][8] = {};

  // ---- K-loop: 8 iters of BK=64, double-buffered B, stage-before-compute --
  for (int k0i = 0; k0i < 8; ++k0i) {
    const bool more = (k0i < 7);
    if (more) {
      stage_B(Bs[(k0i + 1) & 1], Bq, (k0i + 1) * 64, tid);  // async, other buf
      load_AT(Ab, Tb, (k0i + 1) * 64, tid, va, vb);         // regs, early
    }

#pragma unroll
    for (int ks = 0; ks < 2; ++ks) {
      long af[4], bfr[8];
#pragma unroll
      for (int i = 0; i < 4; ++i) {
        const int ar = wm * 64 + i * 16 + (lane & 15);
        const int c8 = ks * 4 + (lane >> 4);
        af[i] = *(const long*)(As + (ar << 6) + ((c8 ^ (ar & 7)) << 3));
      }
#pragma unroll
      for (int n = 0; n < 8; ++n) {
        const int br = wn * 128 + n * 16 + (lane & 15);
        const int c8 = ks * 4 + (lane >> 4);
        bfr[n] = *(const long*)(Bs[k0i & 1] + (br << 6) +
                                (((c8 >> 1) ^ (br & 3)) << 4) + ((c8 & 1) << 3));
      }
#pragma unroll
      for (int mi = 0; mi < 4; ++mi)
#pragma unroll
        for (int ni = 0; ni < 8; ++ni)
          acc[mi][ni] = __builtin_amdgcn_mfma_f32_16x16x32_fp8_fp8(
              af[mi], bfr[ni], acc[mi][ni], 0, 0, 0);
    }

    __syncthreads();   // drains stageB(t+1)+loadA(t+1) — hidden under compute
    if (more) {
      writeA_stats(As, va, vb, tid, cc, tt, ct);  // short VALU+LDS window
      __syncthreads();                            // As(t+1) visible
    }
  }

  // ---- stats reduction (16-lane groups; rows j*32+(tid>>4)) ----
#pragma unroll
  for (int j = 0; j < 4; ++j) {
#pragma unroll
    for (int m = 1; m < 16; m <<= 1) {
      cc[j] += __shfl_xor(cc[j], m);
      tt[j] += __shfl_xor(tt[j], m);
      ct[j] += __shfl_xor(ct[j], m);
    }
    if ((tid & 15) == 0) {
      const int row = j * 32 + (tid >> 4);
      const float nc = fmaxf(sqrtf(cc[j]), EPSF);
      const float nt = fmaxf(sqrtf(tt[j]), EPSF);
      s_invc[row] = 1.f / nc;
      rt[b * T_ + mt * 128 + row] = ct[j] / (nt * nc);
    }
  }
  __syncthreads();

  // ---- epilogue: exp(acc*invc*invd) row-sum over all 512 cols ----
  float invd[8];
#pragma unroll
  for (int ni = 0; ni < 8; ++ni)
    invd[ni] = s_invd[wn * 128 + ni * 16 + (lane & 15)];

#pragma unroll
  for (int mi = 0; mi < 4; ++mi) {
    const int t0l = wm * 64 + mi * 16 + ((lane >> 4) << 2);  // local row
#pragma unroll
    for (int r = 0; r < 4; ++r) {
      const float invc = s_invc[t0l + r];
      float s = 0.f;
#pragma unroll
      for (int ni = 0; ni < 8; ++ni)
        s += __expf(acc[mi][ni][r] * invc * invd[ni]);
      s += __shfl_xor(s, 1);
      s += __shfl_xor(s, 2);
      s += __shfl_xor(s, 4);
      s += __shfl_xor(s, 8);
      if ((lane & 15) == 0)
        atomicAdd(&S[b * T_ + mt * 128 + t0l + r], s);
    }
  }
}

// ---------------------------------------------------------------------------
// Kernel C: loss = sum_{b,t} log(S + exp(r_t)) - r_t
// ---------------------------------------------------------------------------
__global__ void final_loss(const float* __restrict__ S,
                           const float* __restrict__ rt,
                           float* __restrict__ out) {
  const int tid = threadIdx.x;
  float sum = 0.f;
  for (int i = blockIdx.x * blockDim.x + tid; i < B_ * T_;
       i += gridDim.x * blockDim.x) {
    const float r = rt[i];
    sum += logf(S[i] + __expf(r)) - r;
  }
#pragma unroll
  for (int m = 32; m; m >>= 1) sum += __shfl_xor(sum, m);
  __shared__ float ws[4];
  if ((tid & 63) == 0) ws[tid >> 6] = sum;
  __syncthreads();
  if (tid == 0) atomicAdd(out, ws[0] + ws[1] + ws[2] + ws[3]);
}

// ---------------------------------------------------------------------------
extern "C" void kernel_launch(void* const* d_in, const int* in_sizes, int n_in,
                              void* d_out, int out_size, void* d_ws, size_t ws_size,
                              hipStream_t stream) {
  (void)in_sizes; (void)n_in; (void)out_size; (void)ws_size;
  const float* c  = (const float*)d_in[0];
  const float* yt = (const float*)d_in[1];
  const float* yd = (const float*)d_in[2];
  float* out = (float*)d_out;

  // ws layout: [ydq: B*N*D u8][rt: B*T f][inv_nd: B*N f][S: B*T f]
  const size_t ydq_n = (size_t)B_ * N_ * D_;    // 4.2M bytes = 4 MiB
  unsigned char* ydq = (unsigned char*)d_ws;
  float* rt     = (float*)(ydq + ydq_n);        // B*T
  float* inv_nd = rt + B_ * T_;                 // B*N
  float* S      = inv_nd + B_ * N_;             // B*T

  hipMemsetAsync(S, 0, (size_t)B_ * T_ * sizeof(float), stream);
  hipMemsetAsync(out, 0, sizeof(float), stream);

  rownorms_d<<<B_ * N_ / 16, 256, 0, stream>>>(yd, inv_nd, ydq);

  dim3 gF(T_ / 128, B_);   // (32, 16) = 512 blocks, 512 threads
  fused_ct<<<gF, 512, 0, stream>>>(c, yt, ydq, inv_nd, rt, S);

  final_loss<<<64, 256, 0, stream>>>(S, rt, out);
}

// Round 16
// 94.484 us; speedup vs baseline: 4.3303x; 1.0075x over previous
//
#include <hip/hip_runtime.h>
#include <hip/hip_bf16.h>

// Shapes are fixed by the problem definition.
#define B_   16
#define T_   4096
#define N_   512
#define D_   512
#define EPSF 1e-8f

typedef __attribute__((ext_vector_type(8))) short bf16x8; // 8 bf16 = 4 VGPRs
typedef __attribute__((ext_vector_type(4))) float f32x4;

// round-to-nearest-even f32 -> bf16, packed pair into one u32
__device__ __forceinline__ unsigned int pack2bf(float a, float b) {
  unsigned int ua = __float_as_uint(a);
  ua += 0x7fffu + ((ua >> 16) & 1u);
  unsigned int ub = __float_as_uint(b);
  ub += 0x7fffu + ((ub >> 16) & 1u);
  return (ua >> 16) | (ub & 0xffff0000u);
}

// async global->LDS, 16 B per lane
__device__ __forceinline__ void gload_lds16(const void* g, void* l) {
  __builtin_amdgcn_global_load_lds(
      (const __attribute__((address_space(1))) unsigned int*)g,
      (__attribute__((address_space(3))) unsigned int*)l, 16, 0, 0);
}

// ---------------------------------------------------------------------------
// Kernel A: distractor rows -> inv_nd (f32 norms) + bf16 copy (ydbf).
// ---------------------------------------------------------------------------
__global__ void rownorms_d(const float* __restrict__ yd,
                           float* __restrict__ inv_nd,
                           unsigned short* __restrict__ ydbf) {
  const int tid = threadIdx.x;
  const int g   = tid >> 4;
  const int t   = tid & 15;
  const int row = blockIdx.x * 16 + g;
  const float* dr = yd + (size_t)row * D_;
  unsigned short* ob = ydbf + (size_t)row * D_;

  float dd = 0.f;
#pragma unroll
  for (int k = 0; k < 8; ++k) {
    const int col = k * 64 + t * 4;
    float4 a = *(const float4*)(dr + col);
    dd += a.x * a.x + a.y * a.y + a.z * a.z + a.w * a.w;
    uint2 p;
    p.x = pack2bf(a.x, a.y);
    p.y = pack2bf(a.z, a.w);
    *(uint2*)(ob + col) = p;
  }
#pragma unroll
  for (int m = 1; m < 16; m <<= 1) dd += __shfl_xor(dd, m);
  if (t == 0) inv_nd[row] = 1.f / fmaxf(sqrtf(dd), EPSF);
}

// B staging: r6-verbatim addressing (verified, 0 conflicts). 512x64 bf16.
__device__ __forceinline__ void stage_B(unsigned char* buf,
                                        const unsigned short* __restrict__ Bb,
                                        int k0, int tid) {
#pragma unroll
  for (int j = 0; j < 8; ++j) {
    const int g   = j * 512 + tid;          // chunk 0..4095 (16 B each)
    const int row = g >> 3;                 // 8 chunks per 64-bf16 row
    const int sch = (g & 7) ^ (row & 7);    // inverse-swizzled source chunk
    gload_lds16(Bb + (size_t)row * D_ + k0 + (sch << 3), buf + (g << 4));
  }
}

// A+T: issue 4 float4 of c and 4 float4 of yt into regs (early issue).
__device__ __forceinline__ void load_AT(const float* __restrict__ Ab,
                                        const float* __restrict__ Tb,
                                        int k0, int tid,
                                        float4* va, float4* vb) {
#pragma unroll
  for (int j = 0; j < 4; ++j) {
    const int g   = j * 512 + tid;          // float4 0..2047
    const int row = g >> 4;                 // 16 float4 per 64-col row
    const int c4  = g & 15;
    const size_t off = (size_t)row * D_ + k0 + (c4 << 2);
    va[j] = *(const float4*)(Ab + off);
    vb[j] = *(const float4*)(Tb + off);
  }
}

// cvt + swizzled LDS write of A (r1-verified formula) + stats accumulate.
__device__ __forceinline__ void writeA_stats(unsigned char* As,
                                             const float4* va, const float4* vb,
                                             int tid,
                                             float* cc, float* tt, float* ct) {
#pragma unroll
  for (int j = 0; j < 4; ++j) {
    const int g   = j * 512 + tid;
    const int row = g >> 4;
    const int c4  = g & 15;
    const int off = (row << 7) + ((((c4 >> 1) ^ (row & 7))) << 4) + ((c4 & 1) << 3);
    uint2 pa;
    pa.x = pack2bf(va[j].x, va[j].y);
    pa.y = pack2bf(va[j].z, va[j].w);
    *(uint2*)(As + off) = pa;
    cc[j] += va[j].x * va[j].x + va[j].y * va[j].y + va[j].z * va[j].z + va[j].w * va[j].w;
    tt[j] += vb[j].x * vb[j].x + vb[j].y * vb[j].y + vb[j].z * vb[j].z + vb[j].w * vb[j].w;
    ct[j] += va[j].x * vb[j].x + va[j].y * vb[j].y + va[j].z * vb[j].z + va[j].w * vb[j].w;
  }
}

// ---------------------------------------------------------------------------
// Kernel B (final = r11, best verified at 91.9 us bench).
// One block per (mt,b) = 128 rows x N=512; stats folded into A staging
// (c and yt each read exactly once); B double-buffered via global_load_lds,
// staged before compute. Session conclusion: duration tracks L2-MISS bytes
// at the ~3.3 TB/s effective delivery rate (L3 and HBM deliver at the same
// rate; scheduling/occupancy/phase variants r5-r9 all neutral; L2-hit byte
// cuts r13/r15 neutral). Irreducible traffic c+yt = 256 MB f32 -> ~82 us
// floor for this kernel; measured ~84-85 us. At roofline within ~2-3%.
// ---------------------------------------------------------------------------
__launch_bounds__(512, 2)
__global__ void fused_ct(const float* __restrict__ c,
                         const float* __restrict__ yt,
                         const unsigned short* __restrict__ ydbf,
                         const float* __restrict__ inv_nd,
                         float* __restrict__ rt,
                         float* __restrict__ S) {
  __shared__ __align__(16) unsigned char As[128 * 64 * 2];       // 16 KB
  __shared__ __align__(16) unsigned char Bs[2][512 * 64 * 2];    // 2x64 KB
  __shared__ float s_invc[128];
  __shared__ float s_invd[512];

  const int mt = blockIdx.x;
  const int b  = blockIdx.y;
  const int tid  = threadIdx.x;
  const int lane = tid & 63;
  const int w    = tid >> 6;
  const int wm   = w >> 2, wn = w & 3;   // 2 x 4 waves over 128 x 512 out

  const float* Ab = c  + ((size_t)b * T_ + (size_t)mt * 128) * D_;
  const float* Tb = yt + ((size_t)b * T_ + (size_t)mt * 128) * D_;
  const unsigned short* Bb = ydbf + (size_t)b * N_ * D_;

  float4 va[4], vb[4];
  float cc[4] = {0.f, 0.f, 0.f, 0.f};
  float tt[4] = {0.f, 0.f, 0.f, 0.f};
  float ct[4] = {0.f, 0.f, 0.f, 0.f};

  // ---- prologue: iter-0 staging ----
  stage_B(Bs[0], Bb, 0, tid);            // async into Bs[0]
  load_AT(Ab, Tb, 0, tid, va, vb);
  s_invd[tid] = inv_nd[b * N_ + tid];
  writeA_stats(As, va, vb, tid, cc, tt, ct);
  __syncthreads();                       // As visible; Bs[0] gloads drained

  f32x4 acc[4][8] = {};

  // ---- K-loop: 8 iters of BK=64, double-buffered B, stage-before-compute --
  for (int k0i = 0; k0i < 8; ++k0i) {
    const bool more = (k0i < 7);
    if (more) {
      stage_B(Bs[(k0i + 1) & 1], Bb, (k0i + 1) * 64, tid);  // async, other buf
      load_AT(Ab, Tb, (k0i + 1) * 64, tid, va, vb);         // regs, early
    }

#pragma unroll
    for (int ks = 0; ks < 2; ++ks) {
      bf16x8 af[4], bfr[8];
#pragma unroll
      for (int i = 0; i < 4; ++i) {
        const int ar  = wm * 64 + i * 16 + (lane & 15);
        const int ach = (ks * 4 + (lane >> 4)) ^ (ar & 7);
        af[i] = *(const bf16x8*)(As + (ar << 7) + (ach << 4));
      }
#pragma unroll
      for (int n = 0; n < 8; ++n) {
        const int br  = wn * 128 + n * 16 + (lane & 15);
        const int bch = (ks * 4 + (lane >> 4)) ^ (br & 7);
        bfr[n] = *(const bf16x8*)(Bs[k0i & 1] + (br << 7) + (bch << 4));
      }
#pragma unroll
      for (int mi = 0; mi < 4; ++mi)
#pragma unroll
        for (int ni = 0; ni < 8; ++ni)
          acc[mi][ni] = __builtin_amdgcn_mfma_f32_16x16x32_bf16(
              af[mi], bfr[ni], acc[mi][ni], 0, 0, 0);
    }

    __syncthreads();   // drains stageB(t+1)+loadA(t+1) — hidden under compute
    if (more) {
      writeA_stats(As, va, vb, tid, cc, tt, ct);  // short VALU+LDS window
      __syncthreads();                            // As(t+1) visible
    }
  }

  // ---- stats reduction (16-lane groups; rows j*32+(tid>>4)) ----
#pragma unroll
  for (int j = 0; j < 4; ++j) {
#pragma unroll
    for (int m = 1; m < 16; m <<= 1) {
      cc[j] += __shfl_xor(cc[j], m);
      tt[j] += __shfl_xor(tt[j], m);
      ct[j] += __shfl_xor(ct[j], m);
    }
    if ((tid & 15) == 0) {
      const int row = j * 32 + (tid >> 4);
      const float nc = fmaxf(sqrtf(cc[j]), EPSF);
      const float nt = fmaxf(sqrtf(tt[j]), EPSF);
      s_invc[row] = 1.f / nc;
      rt[b * T_ + mt * 128 + row] = ct[j] / (nt * nc);
    }
  }
  __syncthreads();

  // ---- epilogue: exp(acc*invc*invd) row-sum over all 512 cols ----
  float invd[8];
#pragma unroll
  for (int ni = 0; ni < 8; ++ni)
    invd[ni] = s_invd[wn * 128 + ni * 16 + (lane & 15)];

#pragma unroll
  for (int mi = 0; mi < 4; ++mi) {
    const int t0l = wm * 64 + mi * 16 + ((lane >> 4) << 2);  // local row
#pragma unroll
    for (int r = 0; r < 4; ++r) {
      const float invc = s_invc[t0l + r];
      float s = 0.f;
#pragma unroll
      for (int ni = 0; ni < 8; ++ni)
        s += __expf(acc[mi][ni][r] * invc * invd[ni]);
      s += __shfl_xor(s, 1);
      s += __shfl_xor(s, 2);
      s += __shfl_xor(s, 4);
      s += __shfl_xor(s, 8);
      if ((lane & 15) == 0)
        atomicAdd(&S[b * T_ + mt * 128 + t0l + r], s);
    }
  }
}

// ---------------------------------------------------------------------------
// Kernel C: loss = sum_{b,t} log(S + exp(r_t)) - r_t
// ---------------------------------------------------------------------------
__global__ void final_loss(const float* __restrict__ S,
                           const float* __restrict__ rt,
                           float* __restrict__ out) {
  const int tid = threadIdx.x;
  float sum = 0.f;
  for (int i = blockIdx.x * blockDim.x + tid; i < B_ * T_;
       i += gridDim.x * blockDim.x) {
    const float r = rt[i];
    sum += logf(S[i] + __expf(r)) - r;
  }
#pragma unroll
  for (int m = 32; m; m >>= 1) sum += __shfl_xor(sum, m);
  __shared__ float ws[4];
  if ((tid & 63) == 0) ws[tid >> 6] = sum;
  __syncthreads();
  if (tid == 0) atomicAdd(out, ws[0] + ws[1] + ws[2] + ws[3]);
}

// ---------------------------------------------------------------------------
extern "C" void kernel_launch(void* const* d_in, const int* in_sizes, int n_in,
                              void* d_out, int out_size, void* d_ws, size_t ws_size,
                              hipStream_t stream) {
  (void)in_sizes; (void)n_in; (void)out_size; (void)ws_size;
  const float* c  = (const float*)d_in[0];
  const float* yt = (const float*)d_in[1];
  const float* yd = (const float*)d_in[2];
  float* out = (float*)d_out;

  // ws layout: [ydbf: B*N*D u16][rt: B*T f][inv_nd: B*N f][S: B*T f]
  const size_t ydbf_n = (size_t)B_ * N_ * D_;   // 4.2M u16 = 8 MiB
  unsigned short* ydbf = (unsigned short*)d_ws;
  float* rt     = (float*)(ydbf + ydbf_n);      // B*T
  float* inv_nd = rt + B_ * T_;                 // B*N
  float* S      = inv_nd + B_ * N_;             // B*T

  hipMemsetAsync(S, 0, (size_t)B_ * T_ * sizeof(float), stream);
  hipMemsetAsync(out, 0, sizeof(float), stream);

  rownorms_d<<<B_ * N_ / 16, 256, 0, stream>>>(yd, inv_nd, ydbf);

  dim3 gF(T_ / 128, B_);   // (32, 16) = 512 blocks, 512 threads
  fused_ct<<<gF, 512, 0, stream>>>(c, yt, ydbf, inv_nd, rt, S);

  final_loss<<<64, 256, 0, stream>>>(S, rt, out);
}